// Round 9
// baseline (349.177 us; speedup 1.0000x reference)
//
#include <hip/hip_runtime.h>
#include <math.h>

#define N_NODES 50000
#define N_EDGES 800000
#define DIM 256
#define HEADS 8
#define DIM_OUT 32
#define INNER 256        // HEADS*DIM_OUT
#define M_PAD 50048      // 391 * 128

typedef __attribute__((ext_vector_type(8))) short bf16x8;
typedef __attribute__((ext_vector_type(4))) float f32x4;
typedef __attribute__((ext_vector_type(2))) float f32x2;

// round-to-nearest-even f32 -> bf16 bits
__device__ __forceinline__ unsigned short f2bf(float f) {
    unsigned u = __float_as_uint(f);
    unsigned r = (u + 0x7FFFu + ((u >> 16) & 1u)) >> 16;
    return (unsigned short)r;
}

// unpack uint (2 packed bf16) -> f32x2
__device__ __forceinline__ f32x2 up2(unsigned u) {
    f32x2 r;
    r.x = __uint_as_float(u << 16);
    r.y = __uint_as_float(u & 0xFFFF0000u);
    return r;
}
__device__ __forceinline__ void up2x4(uint4 r, f32x2* o) {
    o[0] = up2(r.x); o[1] = up2(r.y); o[2] = up2(r.z); o[3] = up2(r.w);
}

// global -> LDS direct copy, 16 B per lane, dest = wave-uniform base + lane*16
__device__ __forceinline__ void gll16(const void* g, void* l) {
    __builtin_amdgcn_global_load_lds(
        (const __attribute__((address_space(1))) unsigned*)(uintptr_t)g,
        (__attribute__((address_space(3))) unsigned*)(unsigned)(uintptr_t)l,
        16, 0, 0);
}

// ---------------------------------------------------------------------------
// prep (conv_x removed — x->bf16 fused into gemm A-staging):
// conv_w (768 blocks) + deg_hist+rank (3125 blocks), one dispatch.
// The histogram's atomicAdd return value IS the edge's rank within its dst
// bucket -> stored to rank[] so csr_scatter needs no atomics.
// ---------------------------------------------------------------------------
#define NB_CONVW 768    // 3*65536/256
#define NB_HIST  3125   // N_EDGES/256
__global__ __launch_bounds__(256) void prep(
    const float* __restrict__ Wq, const float* __restrict__ Wk,
    const float* __restrict__ Wv,
    const int* __restrict__ dst,
    unsigned short* __restrict__ Wt,
    int* __restrict__ deg, int* __restrict__ rank)
{
    int b = blockIdx.x;
    if (b < NB_CONVW) {
        int idx = b * 256 + threadIdx.x;                // < 3*65536
        int z = idx >> 16, r = idx & 65535;
        int k = r >> 8, n = r & 255;
        const float* W = (z == 0) ? Wq : (z == 1) ? Wk : Wv;
        Wt[(size_t)z * 65536 + n * 256 + k] = f2bf(W[k * 256 + n]);
    } else {
        int e = (b - NB_CONVW) * 256 + threadIdx.x;
        if (e < N_EDGES) rank[e] = atomicAdd(deg + dst[e], 1);
    }
}

// ---------------------------------------------------------------------------
// Fused QKV GEMM, BM=128 x BN=256, BK=32, 512 threads (8 waves, 2Mx4N),
// DOUBLE-BUFFERED LDS (R7-proven 2-phase). A is staged from x (f32)
// directly — reg-load + f2bf + ds_write_b128 — deleting prep's conv_x pass
// and the 77 MB xbf round-trip. T14 split: A-loads for step s+1 issue BEFORE
// the barrier (pure global reads, no LDS hazard), the ds_write lands after
// (buffer cur^1 is protected by the barrier). B stays global_load_lds.
// Rows >= N_NODES: address clamped to row 0, values zeroed (pad semantics).
// Block 0 runs the rowptr scan concurrently (R7-proven).
// ---------------------------------------------------------------------------
#define GEMM_NWG 1173   // 391 panels * 3 z
__global__ __launch_bounds__(512) void gemm_qkv(
    const float* __restrict__ x,
    const unsigned short* __restrict__ Wt,   // [3][n][k] bf16
    const float* __restrict__ bq, const float* __restrict__ bk,
    const float* __restrict__ bv,
    unsigned short* __restrict__ q, unsigned short* __restrict__ k,
    unsigned short* __restrict__ v,
    const int* __restrict__ deg, int* __restrict__ rowptr)
{
    const int t = threadIdx.x;

    if (blockIdx.x == 0) {
        // ---- embedded rowptr scan: 512 threads, 2048-int tiles, 25 tiles ----
        __shared__ int wsum[8];
        __shared__ int wpre[9];
        int wid = t >> 6, ln = t & 63;
        int carry = 0;
        for (int base = 0; base < N_NODES; base += 2048) {
            int i4 = base + t * 4;
            int4 dv = {0, 0, 0, 0};
            if (i4 < N_NODES) dv = *(const int4*)(deg + i4);  // N_NODES%4==0
            int sum = dv.x + dv.y + dv.z + dv.w;
            int inc = sum;
            #pragma unroll
            for (int off = 1; off < 64; off <<= 1) {
                int u = __shfl_up(inc, off);
                if (ln >= off) inc += u;
            }
            if (ln == 63) wsum[wid] = inc;
            __syncthreads();
            if (t == 0) {
                int a = 0;
                #pragma unroll
                for (int j = 0; j < 8; j++) { wpre[j] = a; a += wsum[j]; }
                wpre[8] = a;
            }
            __syncthreads();
            if (i4 < N_NODES) {
                int r = carry + wpre[wid] + (inc - sum);
                r += dv.x; rowptr[i4 + 1] = r;
                r += dv.y; rowptr[i4 + 2] = r;
                r += dv.z; rowptr[i4 + 3] = r;
                r += dv.w; rowptr[i4 + 4] = r;
            }
            carry += wpre[8];
            __syncthreads();        // protect wsum for next tile
        }
        if (t == 0) rowptr[0] = 0;
        return;
    }

    // XCD-chunked bijective remap over the 1173 gemm blocks (q8=146, r8=5)
    int hw = blockIdx.x - 1;
    int xcd = hw & 7, pos = hw >> 3;
    int lid = (xcd < 5 ? xcd * 147 : 5 * 147 + (xcd - 5) * 146) + pos;
    int panel = lid / 3;            // A row-panel index (z fastest)
    int z = lid - panel * 3;
    const int row0 = panel * 128;

    const unsigned short* Wz = Wt + (size_t)z * 65536;
    const float* bias = (z == 0) ? bq : (z == 1) ? bk : bv;
    unsigned short* C = (z == 0) ? q : (z == 1) ? k : v;

    __shared__ __align__(16) short As[2][128 * 32];   // 8 KB x2
    __shared__ __align__(16) short Bs[2][256 * 32];   // 16 KB x2

    const int wave = t >> 6;          // 0..7
    const int lane = t & 63;
    const int wm = (wave & 1) * 64;
    const int wn = (wave >> 1) * 64;  // 0,64,128,192
    const int lr = lane & 15;
    const int lg = lane >> 4;
    const int srow = lane >> 2;       // staging: row within 16-row segment
    const int sch  = lane & 3;        // staging: 16-B chunk within row

    // A staging source (f32): row = row0 + wave*16 + srow, 8 cols at sch*8
    const int arow = row0 + wave * 16 + srow;
    const bool avalid = arow < N_NODES;
    const float* aptr = x + (size_t)(avalid ? arow : 0) * 256 + sch * 8;
    // LDS dest offset (shorts), same layout gll16 produced: lane*8 shorts
    const int aoff = wave * 512 + srow * 32 + sch * 8;

    f32x4 acc[4][4] = {};

#define LOADA(RA, RB, K)                                                     \
    do {                                                                     \
        RA = *(const float4*)(aptr + (K));                                   \
        RB = *(const float4*)(aptr + (K) + 4);                               \
        if (!avalid) { RA = {0,0,0,0}; RB = {0,0,0,0}; }                     \
    } while (0)

#define WRITEA(B, RA, RB)                                                    \
    do {                                                                     \
        uint4 o_;                                                            \
        o_.x = (unsigned)f2bf(RA.x) | ((unsigned)f2bf(RA.y) << 16);          \
        o_.y = (unsigned)f2bf(RA.z) | ((unsigned)f2bf(RA.w) << 16);         \
        o_.z = (unsigned)f2bf(RB.x) | ((unsigned)f2bf(RB.y) << 16);         \
        o_.w = (unsigned)f2bf(RB.z) | ((unsigned)f2bf(RB.w) << 16);         \
        *(uint4*)&As[B][aoff] = o_;                                          \
    } while (0)

// stage B K-tile at col K into buffer BUF: segs 2w, 2w+1
#define STAGEB(BUF, K)                                                       \
    do {                                                                     \
        gll16(Wz + (size_t)(wave * 32 + srow) * 256 + (K) + sch * 8,         \
              &Bs[BUF][wave * 1024]);                                        \
        gll16(Wz + (size_t)(wave * 32 + 16 + srow) * 256 + (K) + sch * 8,    \
              &Bs[BUF][wave * 1024 + 512]);                                  \
    } while (0)

    // prologue: stage tile 0
    float4 ra, rb;
    LOADA(ra, rb, 0);
    STAGEB(0, 0);
    WRITEA(0, ra, rb);

    #pragma unroll
    for (int s = 0; s < 8; s++) {
        const int cur = s & 1;
        if (s < 7) LOADA(ra, rb, (s + 1) * 32);    // pure global reads: pre-barrier
        __syncthreads();              // drains stage of buffer cur (vm+lgkm)
        if (s < 7) {
            STAGEB(cur ^ 1, (s + 1) * 32);
            WRITEA(cur ^ 1, ra, rb);  // overlaps with MFMA below
        }
        bf16x8 af[4], bfr[4];
        #pragma unroll
        for (int mi = 0; mi < 4; mi++)
            af[mi] = *(const bf16x8*)&As[cur][(wm + mi * 16 + lr) * 32 + lg * 8];
        #pragma unroll
        for (int ni = 0; ni < 4; ni++)
            bfr[ni] = *(const bf16x8*)&Bs[cur][(wn + ni * 16 + lr) * 32 + lg * 8];
        #pragma unroll
        for (int mi = 0; mi < 4; mi++)
            #pragma unroll
            for (int ni = 0; ni < 4; ni++)
                acc[mi][ni] = __builtin_amdgcn_mfma_f32_16x16x32_bf16(
                    af[mi], bfr[ni], acc[mi][ni], 0, 0, 0);
    }
#undef LOADA
#undef WRITEA
#undef STAGEB

    // epilogue: C/D layout col=lane&15, row=(lane>>4)*4+reg  [m89-verified]
    #pragma unroll
    for (int mi = 0; mi < 4; mi++) {
        #pragma unroll
        for (int ni = 0; ni < 4; ni++) {
            int gcol = wn + ni * 16 + lr;
            float bb = bias[gcol];
            #pragma unroll
            for (int r = 0; r < 4; r++) {
                int grow = row0 + wm + mi * 16 + lg * 4 + r;
                if (grow < N_NODES)
                    C[(size_t)grow * 256 + gcol] = f2bf(acc[mi][ni][r] + bb);
            }
        }
    }
}

// csr_scatter, atomic-free: rank[e] (from prep's histogram return) gives the
// unique slot. Reads are coalesced; rowptr gather is 200 KB (L2-resident).
__global__ __launch_bounds__(256) void csr_scatter(
    const int* __restrict__ src, const int* __restrict__ dst,
    const int* __restrict__ rowptr, const int* __restrict__ rank,
    int* __restrict__ edge_src)
{
    int e = blockIdx.x * 256 + threadIdx.x;
    if (e >= N_EDGES) return;
    edge_src[rowptr[dst[e]] + rank[e]] = src[e];
}

// ---------------------------------------------------------------------------
// Fused single-pass attention per dst node (R2-proven exact structure:
// 116.4 us full-size, VGPR 52). Launched as TWO 25k-node dispatches
// (node0 = 0, 25000) — perf-neutral, lowers the rocprof top-5 visibility
// threshold to ~58 us so hidden mid-size kernels surface (diagnostic).
// ---------------------------------------------------------------------------
__global__ __launch_bounds__(256) void node_attn(
    const unsigned short* __restrict__ qbf,
    const unsigned short* __restrict__ kbf,
    const unsigned short* __restrict__ vbf,
    const int* __restrict__ rowptr, const int* __restrict__ edge_src,
    float* __restrict__ out, int node0)
{
    int node = node0 + blockIdx.x * 4 + (threadIdx.x >> 6);
    int lane = threadIdx.x & 63;
    if (node >= N_NODES) return;
    const int half = lane >> 5;
    const int l = lane & 31;

    int beg = rowptr[node], end = rowptr[node + 1];
    int deg = end - beg;

    float* op = out + (size_t)node * 256 + l * 8;
    if (deg <= 0) {               // no incoming edges -> zeros (matches ref)
        if (half == 0) {
            float4 z4 = {0.f, 0.f, 0.f, 0.f};
            *(float4*)op = z4;
            *(float4*)(op + 4) = z4;
        }
        return;
    }

    f32x2 kf2[4];
    up2x4(*(const uint4*)(kbf + (size_t)node * 256 + l * 8), kf2);

    const unsigned short* qrow = qbf + l * 8;   // + id*256 shorts per edge
    const unsigned short* vrow = vbf + l * 8;

    // 1/sqrt(32) * log2(e): softmax runs in exp2 domain (ratios exact)
    const float SC = 0.17677669529663687f * 1.4426950408889634f;

    int U = (deg + 1) >> 1;            // slots per half (half1 may have -1)
    U = ((U + 2) / 3) * 3;             // round up to unroll factor 3
    U = __builtin_amdgcn_readfirstlane(U);   // wave-uniform -> scalar loop

    const int i0 = beg + half;         // this half's stream, stride 2
    const int last = end - 1;          // clamp target (valid: deg >= 1)

    // ramp: rows for slots 0,1; ids for slots 2,3 (slot 4 fetched by body0)
    int tmp0 = edge_src[min(i0,     last)];
    int tmp1 = edge_src[min(i0 + 2, last)];
    int idC  = edge_src[min(i0 + 4, last)];
    int idA  = edge_src[min(i0 + 6, last)];
    int idB  = 0;
    uint4 qA = *(const uint4*)(qrow + (size_t)tmp0 * 256);
    uint4 vA = *(const uint4*)(vrow + (size_t)tmp0 * 256);
    uint4 qB = *(const uint4*)(qrow + (size_t)tmp1 * 256);
    uint4 vB = *(const uint4*)(vrow + (size_t)tmp1 * 256);
    uint4 qC, vC;

    float m = -1e30f, zsum = 0.0f;
    f32x2 af2[4] = {};

// body for slot t+P: compute from (QW,VW); load rows of slot t+P+2 into
// (QL,VL) via IDL; fetch id of slot t+P+4 into IDF.
#define BODY(QW, VW, QL, VL, IDL, IDF, P)                                    \
    do {                                                                     \
        size_t off_ = (size_t)(IDL) * 256;                                   \
        QL = *(const uint4*)(qrow + off_);                                   \
        VL = *(const uint4*)(vrow + off_);                                   \
        int vi_ = i0 + 2 * t + 2 * (P);                                      \
        IDF = edge_src[min(vi_ + 8, last)];                                  \
        f32x2 qf_[4], vf_[4];                                                \
        up2x4(QW, qf_);                                                      \
        up2x4(VW, vf_);                                                      \
        f32x2 d_ = qf_[0] * kf2[0];                                          \
        d_ += qf_[1] * kf2[1];                                               \
        d_ += qf_[2] * kf2[2];                                               \
        d_ += qf_[3] * kf2[3];                                               \
        float s_ = d_.x + d_.y;                                              \
        s_ += __shfl_xor(s_, 1);                                             \
        s_ += __shfl_xor(s_, 2);                                             \
        bool ok_ = vi_ < end;                                                \
        float sc_ = ok_ ? s_ * SC : -1e30f;                                  \
        float mn_ = fmaxf(m, sc_);                                           \
        float w_ = exp2f(sc_ - mn_);                                         \
        w_ = ok_ ? w_ : 0.0f;                                                \
        float al_ = exp2f(m - mn_);                                          \
        zsum = zsum * al_ + w_;                                              \
        f32x2 a2_ = {al_, al_}, w2_ = {w_, w_};                              \
        af2[0] = af2[0] * a2_ + vf_[0] * w2_;                                \
        af2[1] = af2[1] * a2_ + vf_[1] * w2_;                                \
        af2[2] = af2[2] * a2_ + vf_[2] * w2_;                                \
        af2[3] = af2[3] * a2_ + vf_[3] * w2_;                                \
        m = mn_;                                                             \
    } while (0)

    for (int t = 0; t < U; t += 3) {
        BODY(qA, vA, qC, vC, idC, idB, 0);
        BODY(qB, vB, qA, vA, idA, idC, 1);
        BODY(qC, vC, qB, vB, idB, idA, 2);
    }
#undef BODY

    // combine halves: rescale to common max, sum across lane^32
    float mo = __shfl_xor(m, 32);
    float mt = fmaxf(m, mo);
    float scale = exp2f(m - mt);       // empty half: exp2(-1e30 - mt) = 0
    zsum *= scale;
    zsum += __shfl_xor(zsum, 32);
    #pragma unroll
    for (int j = 0; j < 4; j++) {
        af2[j].x = af2[j].x * scale;
        af2[j].y = af2[j].y * scale;
        af2[j].x += __shfl_xor(af2[j].x, 32);
        af2[j].y += __shfl_xor(af2[j].y, 32);
    }

    float inv = 1.0f / fmaxf(zsum, 1e-16f);
    if (half == 0) {
        float4 o0 = {af2[0].x * inv, af2[0].y * inv, af2[1].x * inv, af2[1].y * inv};
        float4 o1 = {af2[2].x * inv, af2[2].y * inv, af2[3].x * inv, af2[3].y * inv};
        *(float4*)op = o0;
        *(float4*)(op + 4) = o1;
    }
}

// ---------------------------------------------------------------------------
extern "C" void kernel_launch(void* const* d_in, const int* in_sizes, int n_in,
                              void* d_out, int out_size, void* d_ws, size_t ws_size,
                              hipStream_t stream) {
    const float* x  = (const float*)d_in[0];
    const float* Wq = (const float*)d_in[1];
    const float* bq = (const float*)d_in[2];
    const float* Wk = (const float*)d_in[3];
    const float* bk = (const float*)d_in[4];
    const float* Wv = (const float*)d_in[5];
    const float* bv = (const float*)d_in[6];
    const int* src  = (const int*)d_in[7];
    const int* dst  = (const int*)d_in[8];
    float* out = (float*)d_out;

    unsigned short* qbf = (unsigned short*)d_ws;
    unsigned short* kbf = qbf + (size_t)N_NODES * INNER;
    unsigned short* vbf = kbf + (size_t)N_NODES * INNER;
    unsigned short* Wt  = vbf + (size_t)N_NODES * INNER;   // 3*65536
    int* deg      = (int*)(Wt + 3 * 65536);
    int* rowptr   = deg + N_NODES;
    int* edge_src = rowptr + (N_NODES + 1);
    int* rank     = edge_src + N_EDGES;

    hipMemsetAsync(deg, 0, (size_t)N_NODES * sizeof(int), stream);

    prep<<<NB_CONVW + NB_HIST, 256, 0, stream>>>(
        Wq, Wk, Wv, dst, Wt, deg, rank);

    // gemm (blocks 1..1173, A staged from x directly) + embedded scan (block 0)
    gemm_qkv<<<GEMM_NWG + 1, 512, 0, stream>>>(
        x, Wt, bq, bk, bv, qbf, kbf, vbf, deg, rowptr);

    csr_scatter<<<(N_EDGES + 255) / 256, 256, 0, stream>>>(
        src, dst, rowptr, rank, edge_src);

    // attn split into two 25k-node halves (diagnostic: lowers top-5 threshold)
    node_attn<<<6250, 256, 0, stream>>>(
        qbf, kbf, vbf, rowptr, edge_src, out, 0);
    node_attn<<<6250, 256, 0, stream>>>(
        qbf, kbf, vbf, rowptr, edge_src, out, 25000);
}